// Round 11
// baseline (91.828 us; speedup 1.0000x reference)
//
#include <hip/hip_runtime.h>

// Problem constants (fixed by setup_inputs in the reference)
#define B_  8
#define N_  3072
#define C_  256
#define H_  128
#define W_  96
#define HW_ (H_ * W_)
#define NC_ (B_ * HW_)          // 98304 cells (~78% EMPTY: 0.25 tokens/cell)
#define NT_ (B_ * N_)           // 24576 tokens
#define EPSF 1e-6f

// Gaussian 3x3, sigma=2 (normalized): center, edge, corner
#define KW0 0.13080118f
#define KW1 0.11543166f
#define KW2 0.10186807f

// fused-kernel tiling: block = (b, 8-row y-tile, 32-col x-tile, 64-ch group)
#define CG_ 64                  // channels per block
#define XT_ 32                  // x columns written per block
#define XS_ 34                  // staged columns (32 + 2 halo)
#define RY_ 8                   // output rows per block (sliding window)

// LDS means row is 64 floats (no pad); bank conflicts broken by XOR swizzle.
// SWZ flips bits 2-5 of the channel index per column -> float4 alignment kept.
#define SWZ(xi) (((xi) & 15) << 2)

// ws layout (u32 units) — identical to the round-4-proven 900,104 B layout.
#define OFF_ASTART 0
#define OFF_ACUR   (NC_ + 1)
#define OFF_BSUM   (2 * NC_ + 1)
#define OFF_BOFF   (2 * NC_ + 1 + 384)
#define OFF_TOKS   (2 * NC_ + 1 + 768)
// total = 2*NC_+1+768+NT_ = 221953 u32 = 887,812 B

__device__ __forceinline__ void token_cell(const float* __restrict__ loc, int token,
                                           int& b, int& ix, int& iy) {
    b = token / N_;
    const float lx = fminf(fmaxf(loc[2 * token + 0], -1.0f), 1.0f);
    const float ly = fminf(fmaxf(loc[2 * token + 1], -1.0f), 1.0f);
    const float px = 0.5f * (lx + 1.0f) * (float)W_ - 0.5f;
    const float py = 0.5f * (ly + 1.0f) * (float)H_ - 0.5f;
    ix = (int)rintf(px); ix = min(max(ix, 0), W_ - 1);   // rintf = round-half-even = jnp.round
    iy = (int)rintf(py); iy = min(max(iy, 0), H_ - 1);
}

// Pass 1: histogram tokens into cells
__global__ void count_k(const float* __restrict__ loc, unsigned* __restrict__ cnts) {
    const int token = blockIdx.x * 256 + threadIdx.x;   // NT_ threads
    int b, ix, iy;
    token_cell(loc, token, b, ix, iy);
    atomicAdd(&cnts[b * HW_ + iy * W_ + ix], 1u);
}

// Pass 2a: per-block (256-cell) sums
__global__ void scanA(const unsigned* __restrict__ cnts, unsigned* __restrict__ Bsum) {
    const int i = blockIdx.x * 256 + threadIdx.x;
    int c = (int)cnts[i];
    #pragma unroll
    for (int off = 32; off > 0; off >>= 1) c += __shfl_down(c, off, 64);
    __shared__ int s[4];
    if ((threadIdx.x & 63) == 0) s[threadIdx.x >> 6] = c;
    __syncthreads();
    if (threadIdx.x == 0) Bsum[blockIdx.x] = (unsigned)(s[0] + s[1] + s[2] + s[3]);
}

// Pass 2b: exclusive scan of the 384 block sums (single block)
__global__ void scanB(const unsigned* __restrict__ Bsum, unsigned* __restrict__ Boff) {
    __shared__ unsigned s[512];
    const int t = threadIdx.x;
    const unsigned v = (t < 384) ? Bsum[t] : 0u;
    s[t] = v;
    __syncthreads();
    #pragma unroll
    for (int off = 1; off < 512; off <<= 1) {
        const unsigned a = (t >= off) ? s[t - off] : 0u;
        __syncthreads();
        s[t] += a;
        __syncthreads();
    }
    if (t < 384) Boff[t] = s[t] - v;   // exclusive
}

// Pass 2c: per-block exclusive scan + block offset -> Astart (and cursor copy)
__global__ void scanC(const unsigned* __restrict__ Boff,
                      unsigned* __restrict__ Astart, unsigned* __restrict__ Acur) {
    __shared__ unsigned s[256];
    const int t = threadIdx.x;
    const int i = blockIdx.x * 256 + t;
    const unsigned v = Acur[i];        // counts currently live in Acur
    s[t] = v;
    __syncthreads();
    #pragma unroll
    for (int off = 1; off < 256; off <<= 1) {
        const unsigned a = (t >= off) ? s[t - off] : 0u;
        __syncthreads();
        s[t] += a;
        __syncthreads();
    }
    const unsigned excl = s[t] - v + Boff[blockIdx.x];
    Astart[i] = excl;
    Acur[i]   = excl;                  // cursor starts at bin start
    if (i == 0) Astart[NC_] = NT_;     // total
}

// Pass 3: scatter token ids (packed with x) into bins
__global__ void fill_bins(const float* __restrict__ loc,
                          unsigned* __restrict__ Acur, unsigned* __restrict__ toks) {
    const int token = blockIdx.x * 256 + threadIdx.x;
    int b, ix, iy;
    token_cell(loc, token, b, ix, iy);
    const unsigned pos = atomicAdd(&Acur[b * HW_ + iy * W_ + ix], 1u);
    toks[pos] = ((unsigned)ix << 20) | (unsigned)token;
}

// Gather one row's window into LDS slot: one 35-lane coalesced Astart read
// gives cflag (shfl diff) + walk range; then a batch-4 contiguous CSR walk
// (toks broadcast, xf 256B-coalesced; lane = channel) flushing per-cell means.
__device__ __forceinline__ void gather_row(const float* __restrict__ xf,
        const unsigned* __restrict__ Astart, const unsigned* __restrict__ toks,
        float* __restrict__ Ms, unsigned* __restrict__ Fs,
        int b, int yg, int xs, int cg, int lane) {
    const int cellbase = b * HW_ + yg * W_;
    unsigned a = 0u;
    if (lane < XS_ + 1) {
        int g = xs - 1 + lane;                 // [xs-1, xs+33]
        g = min(max(g, 0), W_);                // Astart[cellbase+W_] = row end
        a = Astart[cellbase + g];
    }
    const unsigned an = __shfl_down(a, 1, 64);
    if (lane < XS_) Fs[lane] = an - a;         // clamped edges diff to 0
    const unsigned p0 = __shfl(a, 0, 64);
    const unsigned p1 = __shfl(a, XS_, 64);

    int cur_xi = -1;
    float acc = 0.0f;
    unsigned cnt = 0u;
    for (unsigned p = p0; p < p1; p += 4) {
        unsigned vv[4]; float ff[4];
        #pragma unroll
        for (int j = 0; j < 4; ++j)
            if (p + j < p1) vv[j] = toks[p + j];
        #pragma unroll
        for (int j = 0; j < 4; ++j)
            if (p + j < p1)
                ff[j] = xf[(size_t)(vv[j] & 0xFFFFFu) * C_ + cg * CG_ + lane];
        #pragma unroll
        for (int j = 0; j < 4; ++j) {
            if (p + j >= p1) break;
            const int xi = (int)(vv[j] >> 20) - xs + 1;   // in [0, 34)
            if (xi != cur_xi) {
                if (cur_xi >= 0)
                    Ms[cur_xi * 64 + (lane ^ SWZ(cur_xi))] = acc / ((float)cnt + EPSF);
                acc = 0.0f; cnt = 0u; cur_xi = xi;
            }
            acc += ff[j]; ++cnt;
        }
    }
    if (cur_xi >= 0)
        Ms[cur_xi * 64 + (lane ^ SWZ(cur_xi))] = acc / ((float)cnt + EPSF);
}

// Pass 4 (FUSED, sliding window): block stages a 3-row ring of per-cell means
// (64 channels) and slides down 8 output rows: each step gathers ONLY row y+1
// (1.25 walks/row vs 3) then fills+writes row y. Empty-neighbor reads carry
// weight 0, so stale slot data (our own finite writes; prologue zero kills
// inherited NaN patterns) is harmless. Single coalesced NCHW write per elem.
__global__ __launch_bounds__(256) void fused_k(const float* __restrict__ xf,
        const unsigned* __restrict__ Astart, const unsigned* __restrict__ toks,
        float* __restrict__ out) {
    const int blk = blockIdx.x;          // ((b*16 + yt)*3 + xt)*4 + cg
    const int cg = blk & 3;
    int rest = blk >> 2;
    const int xt = rest % 3;
    rest /= 3;
    const int yt = rest & 15;
    const int b  = rest >> 4;
    const int y0 = yt * RY_;
    const int xs = xt * XT_;
    const int lane = threadIdx.x & 63;
    const int wv = threadIdx.x >> 6;

    __shared__ __align__(16) float means[3 * XS_ * 64];   // 26112 B
    __shared__ unsigned cflag[3][XS_];

    // one-time zero (kills inherited NaN bit patterns in LDS)
    {
        float4* p4 = (float4*)means;
        for (int i = threadIdx.x; i < 3 * XS_ * 64 / 4; i += 256)
            p4[i] = make_float4(0.f, 0.f, 0.f, 0.f);
    }
    __syncthreads();

    // prologue: stage rows y0-1 -> slot 0, y0 -> slot 1 (parallel on waves 0,1)
    if (wv == 0) {
        if (y0 > 0)
            gather_row(xf, Astart, toks, means, cflag[0], b, y0 - 1, xs, cg, lane);
        else if (lane < XS_) cflag[0][lane] = 0u;
    } else if (wv == 1) {
        gather_row(xf, Astart, toks, means + XS_ * 64, cflag[1], b, y0, xs, cg, lane);
    }
    __syncthreads();

    for (int s = 0; s < RY_; ++s) {
        // gather row y0+s+1 into ring slot (s+2)%3 (overwrites row y0+s-2,
        // whose last reader was the previous step's fill -> barrier below)
        const int sp1 = (s + 2) % 3;
        if (wv == (s & 3)) {
            const int yg = y0 + s + 1;
            if (yg < H_)
                gather_row(xf, Astart, toks, means + sp1 * XS_ * 64, cflag[sp1],
                           b, yg, xs, cg, lane);
            else if (lane < XS_) cflag[sp1][lane] = 0u;
        }
        __syncthreads();

        // fill + write row y = y0+s; ring slots: y-1 -> s%3, y -> (s+1)%3
        {
            const int y = y0 + s;
            const int sm1 = s % 3, s0 = (s + 1) % 3;
            const int xl  = threadIdx.x & 31;
            const int sub = threadIdx.x >> 5;
            const int xi  = xl + 1;          // LDS column of the center cell
            const int c0  = sub * 8;
            const float* M0 = means + sm1 * XS_ * 64;
            const float* M1 = means + s0  * XS_ * 64;
            const float* M2 = means + sp1 * XS_ * 64;
            float* op = out + ((size_t)(b * C_ + cg * CG_ + c0)) * HW_
                            + (size_t)y * W_ + xs + xl;

            if (cflag[s0][xi] != 0u) {       // nonempty: copy normalized mean
                #pragma unroll
                for (int q = 0; q < 2; ++q) {
                    const float4 m = *(const float4*)
                        &M1[xi * 64 + ((c0 + q * 4) ^ SWZ(xi))];
                    op[(size_t)(q * 4 + 0) * HW_] = m.x;
                    op[(size_t)(q * 4 + 1) * HW_] = m.y;
                    op[(size_t)(q * 4 + 2) * HW_] = m.z;
                    op[(size_t)(q * 4 + 3) * HW_] = m.w;
                }
            } else {                         // empty: gaussian-gated blend
                const float w00 = cflag[sm1][xi - 1] ? KW2 : 0.0f;
                const float w01 = cflag[sm1][xi]     ? KW1 : 0.0f;
                const float w02 = cflag[sm1][xi + 1] ? KW2 : 0.0f;
                const float w10 = cflag[s0][xi - 1]  ? KW1 : 0.0f;
                const float w12 = cflag[s0][xi + 1]  ? KW1 : 0.0f;
                const float w20 = cflag[sp1][xi - 1] ? KW2 : 0.0f;
                const float w21 = cflag[sp1][xi]     ? KW1 : 0.0f;
                const float w22 = cflag[sp1][xi + 1] ? KW2 : 0.0f;
                const float ms = ((w00 + w02) + (w20 + w22))
                               + ((w01 + w21) + (w10 + w12));
                const float inv = 1.0f / (ms + EPSF);   // ms==0 -> fs==0 -> 0
                #pragma unroll
                for (int q = 0; q < 2; ++q) {
                    const int cq = c0 + q * 4;
                    const int im = (xi - 1) * 64 + (cq ^ SWZ(xi - 1));
                    const int ic = (xi    ) * 64 + (cq ^ SWZ(xi));
                    const int ip = (xi + 1) * 64 + (cq ^ SWZ(xi + 1));
                    const float4 a0 = *(const float4*)&M0[im];
                    const float4 a1 = *(const float4*)&M0[ic];
                    const float4 a2 = *(const float4*)&M0[ip];
                    const float4 b0 = *(const float4*)&M1[im];
                    const float4 b2 = *(const float4*)&M1[ip];
                    const float4 d0 = *(const float4*)&M2[im];
                    const float4 d1 = *(const float4*)&M2[ic];
                    const float4 d2 = *(const float4*)&M2[ip];
                    float4 fs;
                    fs.x = w00*a0.x + w01*a1.x + w02*a2.x + w10*b0.x + w12*b2.x
                         + w20*d0.x + w21*d1.x + w22*d2.x;
                    fs.y = w00*a0.y + w01*a1.y + w02*a2.y + w10*b0.y + w12*b2.y
                         + w20*d0.y + w21*d1.y + w22*d2.y;
                    fs.z = w00*a0.z + w01*a1.z + w02*a2.z + w10*b0.z + w12*b2.z
                         + w20*d0.z + w21*d1.z + w22*d2.z;
                    fs.w = w00*a0.w + w01*a1.w + w02*a2.w + w10*b0.w + w12*b2.w
                         + w20*d0.w + w21*d1.w + w22*d2.w;
                    op[(size_t)(q * 4 + 0) * HW_] = fs.x * inv;
                    op[(size_t)(q * 4 + 1) * HW_] = fs.y * inv;
                    op[(size_t)(q * 4 + 2) * HW_] = fs.z * inv;
                    op[(size_t)(q * 4 + 3) * HW_] = fs.w * inv;
                }
            }
        }
        __syncthreads();   // protect slot s%3 before next step's gather
    }
}

extern "C" void kernel_launch(void* const* d_in, const int* in_sizes, int n_in,
                              void* d_out, int out_size, void* d_ws, size_t ws_size,
                              hipStream_t stream) {
    const float* x   = (const float*)d_in[0];   // (B, N, C) f32
    const float* loc = (const float*)d_in[1];   // (B, N, 2) f32
    float* out = (float*)d_out;                 // (B, C, H, W) f32

    unsigned* W32 = (unsigned*)d_ws;
    unsigned* Astart = W32 + OFF_ASTART;
    unsigned* Acur   = W32 + OFF_ACUR;
    unsigned* Bsum   = W32 + OFF_BSUM;
    unsigned* Boff   = W32 + OFF_BOFF;
    unsigned* toks   = W32 + OFF_TOKS;

    hipMemsetAsync(Acur, 0, (size_t)NC_ * sizeof(unsigned), stream);

    count_k  <<<NT_ / 256, 256, 0, stream>>>(loc, Acur);
    scanA    <<<NC_ / 256, 256, 0, stream>>>(Acur, Bsum);
    scanB    <<<1, 512, 0, stream>>>(Bsum, Boff);
    scanC    <<<NC_ / 256, 256, 0, stream>>>(Boff, Astart, Acur);
    fill_bins<<<NT_ / 256, 256, 0, stream>>>(loc, Acur, toks);

    // grid = 8*16*3*4 = 1536 = 6 blocks/CU * 256 CUs, fully resident
    fused_k<<<B_ * (H_ / RY_) * 3 * 4, 256, 0, stream>>>(x, Astart, toks, out);
}

// Round 12
// 67.308 us; speedup vs baseline: 1.3643x; 1.3643x over previous
//
#include <hip/hip_runtime.h>

// Problem constants (fixed by setup_inputs in the reference)
#define B_  8
#define N_  3072
#define C_  256
#define H_  128
#define W_  96
#define HW_ (H_ * W_)
#define NC_ (B_ * HW_)          // 98304 cells (~78% EMPTY: 0.25 tokens/cell)
#define NT_ (B_ * N_)           // 24576 tokens
#define EPSF 1e-6f

// Gaussian 3x3, sigma=2 (normalized): center, edge, corner
#define KW0 0.13080118f
#define KW1 0.11543166f
#define KW2 0.10186807f

// fused-kernel tiling: block = (b, y, 32-col x-tile, 64-ch group)  [r10 shape]
#define CG_ 64                  // channels per block
#define XT_ 32                  // x columns written per block
#define XS_ 34                  // staged columns (32 + 2 halo)
#define CPB 72                  // bf16 channel pad (row = 144 B, 16B-aligned)

// ws layout (u32 units) — identical to the round-4-proven 900,104 B layout.
#define OFF_ASTART 0
#define OFF_ACUR   (NC_ + 1)
#define OFF_BSUM   (2 * NC_ + 1)
#define OFF_BOFF   (2 * NC_ + 1 + 384)
#define OFF_TOKS   (2 * NC_ + 1 + 768)
// total = 2*NC_+1+768+NT_ = 221953 u32 = 887,812 B

__device__ __forceinline__ unsigned short f2bf(float f) {   // RNE f32->bf16
    const unsigned u = __float_as_uint(f);
    return (unsigned short)((u + 0x7FFFu + ((u >> 16) & 1u)) >> 16);
}

__device__ __forceinline__ void token_cell(const float* __restrict__ loc, int token,
                                           int& b, int& ix, int& iy) {
    b = token / N_;
    const float lx = fminf(fmaxf(loc[2 * token + 0], -1.0f), 1.0f);
    const float ly = fminf(fmaxf(loc[2 * token + 1], -1.0f), 1.0f);
    const float px = 0.5f * (lx + 1.0f) * (float)W_ - 0.5f;
    const float py = 0.5f * (ly + 1.0f) * (float)H_ - 0.5f;
    ix = (int)rintf(px); ix = min(max(ix, 0), W_ - 1);   // rintf = round-half-even = jnp.round
    iy = (int)rintf(py); iy = min(max(iy, 0), H_ - 1);
}

// Pass 1: histogram tokens into cells
__global__ void count_k(const float* __restrict__ loc, unsigned* __restrict__ cnts) {
    const int token = blockIdx.x * 256 + threadIdx.x;   // NT_ threads
    int b, ix, iy;
    token_cell(loc, token, b, ix, iy);
    atomicAdd(&cnts[b * HW_ + iy * W_ + ix], 1u);
}

// Pass 2a: per-block (256-cell) sums
__global__ void scanA(const unsigned* __restrict__ cnts, unsigned* __restrict__ Bsum) {
    const int i = blockIdx.x * 256 + threadIdx.x;
    int c = (int)cnts[i];
    #pragma unroll
    for (int off = 32; off > 0; off >>= 1) c += __shfl_down(c, off, 64);
    __shared__ int s[4];
    if ((threadIdx.x & 63) == 0) s[threadIdx.x >> 6] = c;
    __syncthreads();
    if (threadIdx.x == 0) Bsum[blockIdx.x] = (unsigned)(s[0] + s[1] + s[2] + s[3]);
}

// Pass 2b: exclusive scan of the 384 block sums (single block)
__global__ void scanB(const unsigned* __restrict__ Bsum, unsigned* __restrict__ Boff) {
    __shared__ unsigned s[512];
    const int t = threadIdx.x;
    const unsigned v = (t < 384) ? Bsum[t] : 0u;
    s[t] = v;
    __syncthreads();
    #pragma unroll
    for (int off = 1; off < 512; off <<= 1) {
        const unsigned a = (t >= off) ? s[t - off] : 0u;
        __syncthreads();
        s[t] += a;
        __syncthreads();
    }
    if (t < 384) Boff[t] = s[t] - v;   // exclusive
}

// Pass 2c: per-block exclusive scan + block offset -> Astart (and cursor copy)
__global__ void scanC(const unsigned* __restrict__ Boff,
                      unsigned* __restrict__ Astart, unsigned* __restrict__ Acur) {
    __shared__ unsigned s[256];
    const int t = threadIdx.x;
    const int i = blockIdx.x * 256 + t;
    const unsigned v = Acur[i];        // counts currently live in Acur
    s[t] = v;
    __syncthreads();
    #pragma unroll
    for (int off = 1; off < 256; off <<= 1) {
        const unsigned a = (t >= off) ? s[t - off] : 0u;
        __syncthreads();
        s[t] += a;
        __syncthreads();
    }
    const unsigned excl = s[t] - v + Boff[blockIdx.x];
    Astart[i] = excl;
    Acur[i]   = excl;                  // cursor starts at bin start
    if (i == 0) Astart[NC_] = NT_;     // total
}

// Pass 3: scatter token ids (packed with x) into bins
__global__ void fill_bins(const float* __restrict__ loc,
                          unsigned* __restrict__ Acur, unsigned* __restrict__ toks) {
    const int token = blockIdx.x * 256 + threadIdx.x;
    int b, ix, iy;
    token_cell(loc, token, b, ix, iy);
    const unsigned pos = atomicAdd(&Acur[b * HW_ + iy * W_ + ix], 1u);
    toks[pos] = ((unsigned)ix << 20) | (unsigned)token;
}

// Gather one row's window into an LDS slot: one 35-lane coalesced Astart read
// gives cflag (shfl diff) + walk range; then a batch-4 contiguous CSR walk
// (toks broadcast, xf 256B-coalesced; lane = channel) flushing bf16 means.
__device__ __forceinline__ void gather_row(const float* __restrict__ xf,
        const unsigned* __restrict__ Astart, const unsigned* __restrict__ toks,
        unsigned short* __restrict__ Ms, unsigned* __restrict__ Fs,
        int b, int yg, int xs, int cg, int lane) {
    const int cellbase = b * HW_ + yg * W_;
    unsigned a = 0u;
    if (lane < XS_ + 1) {
        int g = xs - 1 + lane;                 // [xs-1, xs+33]
        g = min(max(g, 0), W_);                // Astart[cellbase+W_] = row end
        a = Astart[cellbase + g];
    }
    const unsigned an = __shfl_down(a, 1, 64);
    if (lane < XS_) Fs[lane] = an - a;         // clamped edges diff to 0
    const unsigned p0 = __shfl(a, 0, 64);
    const unsigned p1 = __shfl(a, XS_, 64);

    int cur_xi = -1;
    float acc = 0.0f;
    unsigned cnt = 0u;
    for (unsigned p = p0; p < p1; p += 4) {
        unsigned vv[4]; float ff[4];
        #pragma unroll
        for (int j = 0; j < 4; ++j)
            if (p + j < p1) vv[j] = toks[p + j];
        #pragma unroll
        for (int j = 0; j < 4; ++j)
            if (p + j < p1)
                ff[j] = xf[(size_t)(vv[j] & 0xFFFFFu) * C_ + cg * CG_ + lane];
        #pragma unroll
        for (int j = 0; j < 4; ++j) {
            if (p + j >= p1) break;
            const int xi = (int)(vv[j] >> 20) - xs + 1;   // in [0, 34)
            if (xi != cur_xi) {
                if (cur_xi >= 0)
                    Ms[cur_xi * CPB + lane] = f2bf(acc / ((float)cnt + EPSF));
                acc = 0.0f; cnt = 0u; cur_xi = xi;
            }
            acc += ff[j]; ++cnt;
        }
    }
    if (cur_xi >= 0)
        Ms[cur_xi * CPB + lane] = f2bf(acc / ((float)cnt + EPSF));
}

// unpack 4 bf16 (8B, aligned) -> 4 f32
__device__ __forceinline__ void bf4_to_f32(const unsigned short* p, float* f) {
    const uint2 v = *(const uint2*)p;
    f[0] = __uint_as_float(v.x << 16);
    f[1] = __uint_as_float(v.x & 0xFFFF0000u);
    f[2] = __uint_as_float(v.y << 16);
    f[3] = __uint_as_float(v.y & 0xFFFF0000u);
}

// Pass 4 (FUSED, r10 structure): waves 0-2 gather rows y-1..y+1 in PARALLEL
// (cflag folded into the gather via shfl-diff); fill threads map to a FIXED x
// column (weights decoded once) x 8 channels; single coalesced NCHW write.
// LDS means are bf16 (14.7 KB total) -> 8 blocks/CU residency.
__global__ __launch_bounds__(256) void fused_k(const float* __restrict__ xf,
        const unsigned* __restrict__ Astart, const unsigned* __restrict__ toks,
        float* __restrict__ out) {
    const int blk = blockIdx.x;          // ((b*128 + y)*3 + xt)*4 + cg
    const int cg = blk & 3;
    const int t2 = blk >> 2;
    const int xt = t2 % 3;
    const int t3 = t2 / 3;
    const int y  = t3 & 127;
    const int b  = t3 >> 7;
    const int xs = xt * XT_;
    const int lane = threadIdx.x & 63;
    const int wv = threadIdx.x >> 6;

    __shared__ __align__(16) unsigned short means[3 * XS_ * CPB];   // 14688 B
    __shared__ unsigned cflag[3][XS_];

    // zero-init means (bf16 +0.0 = 0x0000)
    {
        uint4* p4 = (uint4*)means;
        #pragma unroll
        for (int i = threadIdx.x; i < 3 * XS_ * CPB / 8; i += 256)
            p4[i] = make_uint4(0u, 0u, 0u, 0u);
    }
    __syncthreads();

    // gather: wave r in {0,1,2} walks row y-1+r (and writes its cflag row)
    if (wv < 3) {
        const int yg = y - 1 + wv;
        if ((unsigned)yg < (unsigned)H_)
            gather_row(xf, Astart, toks, means + wv * XS_ * CPB, cflag[wv],
                       b, yg, xs, cg, lane);
        else if (lane < XS_) cflag[wv][lane] = 0u;
    }
    __syncthreads();

    // fill + write: thread = fixed x column (xl), 8 channels (sub*8..sub*8+7)
    const int xl  = threadIdx.x & 31;
    const int sub = threadIdx.x >> 5;
    const int xi  = xl + 1;              // LDS column of the center cell
    const int c0  = sub * 8;
    const unsigned short* M0 = means;
    const unsigned short* M1 = means + XS_ * CPB;
    const unsigned short* M2 = means + 2 * XS_ * CPB;
    float* op = out + ((size_t)(b * C_ + cg * CG_ + c0)) * HW_
                    + (size_t)y * W_ + xs + xl;

    if (cflag[1][xi] != 0u) {            // nonempty: copy normalized mean
        #pragma unroll
        for (int q = 0; q < 2; ++q) {
            float m[4];
            bf4_to_f32(&M1[xi * CPB + c0 + q * 4], m);
            op[(size_t)(q * 4 + 0) * HW_] = m[0];
            op[(size_t)(q * 4 + 1) * HW_] = m[1];
            op[(size_t)(q * 4 + 2) * HW_] = m[2];
            op[(size_t)(q * 4 + 3) * HW_] = m[3];
        }
    } else {                             // empty: gaussian-gated neighbor blend
        const float w00 = cflag[0][xi - 1] ? KW2 : 0.0f;
        const float w01 = cflag[0][xi]     ? KW1 : 0.0f;
        const float w02 = cflag[0][xi + 1] ? KW2 : 0.0f;
        const float w10 = cflag[1][xi - 1] ? KW1 : 0.0f;
        const float w12 = cflag[1][xi + 1] ? KW1 : 0.0f;
        const float w20 = cflag[2][xi - 1] ? KW2 : 0.0f;
        const float w21 = cflag[2][xi]     ? KW1 : 0.0f;
        const float w22 = cflag[2][xi + 1] ? KW2 : 0.0f;
        const float ms = ((w00 + w02) + (w20 + w22)) + ((w01 + w21) + (w10 + w12));
        const float inv = 1.0f / (ms + EPSF);   // ms==0 -> fs==0 -> 0
        #pragma unroll
        for (int q = 0; q < 2; ++q) {
            const int cq = c0 + q * 4;
            const int im = (xi - 1) * CPB + cq;
            const int ic = (xi    ) * CPB + cq;
            const int ip = (xi + 1) * CPB + cq;
            float a0[4], a1[4], a2[4], b0[4], b2[4], d0[4], d1[4], d2[4];
            bf4_to_f32(&M0[im], a0); bf4_to_f32(&M0[ic], a1); bf4_to_f32(&M0[ip], a2);
            bf4_to_f32(&M1[im], b0);                          bf4_to_f32(&M1[ip], b2);
            bf4_to_f32(&M2[im], d0); bf4_to_f32(&M2[ic], d1); bf4_to_f32(&M2[ip], d2);
            #pragma unroll
            for (int k = 0; k < 4; ++k) {
                const float fs = w00*a0[k] + w01*a1[k] + w02*a2[k]
                               + w10*b0[k] + w12*b2[k]
                               + w20*d0[k] + w21*d1[k] + w22*d2[k];
                op[(size_t)(q * 4 + k) * HW_] = fs * inv;
            }
        }
    }
}

extern "C" void kernel_launch(void* const* d_in, const int* in_sizes, int n_in,
                              void* d_out, int out_size, void* d_ws, size_t ws_size,
                              hipStream_t stream) {
    const float* x   = (const float*)d_in[0];   // (B, N, C) f32
    const float* loc = (const float*)d_in[1];   // (B, N, 2) f32
    float* out = (float*)d_out;                 // (B, C, H, W) f32

    unsigned* W32 = (unsigned*)d_ws;
    unsigned* Astart = W32 + OFF_ASTART;
    unsigned* Acur   = W32 + OFF_ACUR;
    unsigned* Bsum   = W32 + OFF_BSUM;
    unsigned* Boff   = W32 + OFF_BOFF;
    unsigned* toks   = W32 + OFF_TOKS;

    hipMemsetAsync(Acur, 0, (size_t)NC_ * sizeof(unsigned), stream);

    count_k  <<<NT_ / 256, 256, 0, stream>>>(loc, Acur);
    scanA    <<<NC_ / 256, 256, 0, stream>>>(Acur, Bsum);
    scanB    <<<1, 512, 0, stream>>>(Bsum, Boff);
    scanC    <<<NC_ / 256, 256, 0, stream>>>(Boff, Astart, Acur);
    fill_bins<<<NT_ / 256, 256, 0, stream>>>(loc, Acur, toks);

    fused_k<<<B_ * H_ * 3 * 4, 256, 0, stream>>>(x, Astart, toks, out);
}